// Round 2
// baseline (148.739 us; speedup 1.0000x reference)
//
#include <hip/hip_runtime.h>

#define DDIM 256
#define HDIM 128
#define KLEN 1024
// 2*log2(e): exp2(SCL*x) == e^{2x}
#define SCL 2.8853900817779268f

// ============ Projection -> Eq/Ek = exp2(SCL * in@W) ============
// v3: classic LDS-tiled GEMM, no scalar-load gamble.
// Block = 64 rows x 64 h, 256 thr, thread = 4r x 4h (16 acc).
// A staged TRANSPOSED At[d][row] (pad 68: read b128 is 2-way = free);
// W staged row-major Wt[d][h] (read is 16-lane broadcast = free).
// Inner d-step: 2 ds_read_b128 + 16 v_fma, imm offsets only -> VALU-bound.
// Grid 544 = 512 key blocks (XCD-swizzled) + 32 query; all co-resident
// (33 KB LDS -> 4 blocks/CU cap, grid 2.1/CU). Global prefetch under compute.
// Output layouts unchanged: Eq row-major [row][128], Ek [b][h][k], exp2 applied.
__global__ __launch_bounds__(256) void proj_kernel(
    const float* __restrict__ queries, const float* __restrict__ keys,
    const float* __restrict__ W_q, const float* __restrict__ W_k,
    float* __restrict__ Eq, float* __restrict__ Ek)
{
    __shared__ union {
        struct { float At[64][68]; float Wt[64][64]; } s;  // 17408 + 16384 B
        float t[64][68];                                   // epilogue transpose
    } sm;

    const int tid = threadIdx.x;
    const int rg  = tid & 15;      // output: 4 rows at rg*4
    const int hg  = tid >> 4;      // output: 4 h at hg*4
    const int sd  = tid & 15;      // staging: 16B granule
    const int sr  = tid >> 4;      // staging: row base (16 rows/pass)

    int blk = blockIdx.x;
    bool iskey; int b = 0, kc0 = 0, hb, row0;
    const float* in; const float* W;
    if (blk < 512) {
        iskey = true;
        int xcd = blk & 7, s = blk >> 3;
        b = ((s >> 5) << 3) | xcd;
        int r5 = s & 31;
        kc0 = (r5 >> 1) << 6;      // 16 k-chunks of 64
        hb  = (r5 & 1) << 6;       // 2 h-halves of 64
        row0 = b * KLEN + kc0;
        in = keys; W = W_k;
    } else {
        iskey = false;
        int qb = blk - 512;        // 0..31
        row0 = (qb >> 1) << 6;
        hb   = (qb & 1) << 6;
        in = queries; W = W_q;
    }

    const float* ga = in + (size_t)(row0 + sr) * DDIM + (sd << 2);
    const float* gw = W + (size_t)sr * HDIM + hb + (sd << 2);

    float4 pfa[4], pfw[4];
    #pragma unroll
    for (int i = 0; i < 4; i++) {
        pfa[i] = *(const float4*)(ga + (size_t)(16 * i) * DDIM);
        pfw[i] = *(const float4*)(gw + (size_t)(16 * i) * HDIM);
    }

    float acc[4][4];
    #pragma unroll
    for (int i = 0; i < 4; i++)
        #pragma unroll
        for (int j = 0; j < 4; j++) acc[i][j] = 0.f;

    for (int dt = 0; dt < DDIM; dt += 64) {
        __syncthreads();           // prior tile's compute done
        #pragma unroll
        for (int i = 0; i < 4; i++) {
            // A transpose-in-LDS: At[d][row]
            sm.s.At[(sd << 2) + 0][sr + 16 * i] = pfa[i].x;
            sm.s.At[(sd << 2) + 1][sr + 16 * i] = pfa[i].y;
            sm.s.At[(sd << 2) + 2][sr + 16 * i] = pfa[i].z;
            sm.s.At[(sd << 2) + 3][sr + 16 * i] = pfa[i].w;
            *(float4*)(&sm.s.Wt[sr + 16 * i][sd << 2]) = pfw[i];
        }
        __syncthreads();
        if (dt < DDIM - 64) {      // prefetch next d-tile under compute
            const float* ga2 = ga + dt + 64;
            const float* gw2 = gw + (size_t)(dt + 64) * HDIM;
            #pragma unroll
            for (int i = 0; i < 4; i++) {
                pfa[i] = *(const float4*)(ga2 + (size_t)(16 * i) * DDIM);
                pfw[i] = *(const float4*)(gw2 + (size_t)(16 * i) * HDIM);
            }
        }
        const float* arp = &sm.s.At[0][rg << 2];
        const float* wrp = &sm.s.Wt[0][hg << 2];
        #pragma unroll 8
        for (int d = 0; d < 64; d++) {
            float4 a4 = *(const float4*)(arp + d * 68);
            float4 w4 = *(const float4*)(wrp + d * 64);
            float av_[4] = {a4.x, a4.y, a4.z, a4.w};
            float wv_[4] = {w4.x, w4.y, w4.z, w4.w};
            #pragma unroll
            for (int i = 0; i < 4; i++)
                #pragma unroll
                for (int j = 0; j < 4; j++)
                    acc[i][j] = fmaf(av_[i], wv_[j], acc[i][j]);
        }
    }

    float e[4][4];
    #pragma unroll
    for (int i = 0; i < 4; i++)
        #pragma unroll
        for (int j = 0; j < 4; j++)
            e[i][j] = __builtin_amdgcn_exp2f(SCL * acc[i][j]);

    if (!iskey) {
        #pragma unroll
        for (int i = 0; i < 4; i++) {
            float* dst = Eq + (size_t)(row0 + (rg << 2) + i) * HDIM + hb + (hg << 2);
            *(float4*)dst = make_float4(e[i][0], e[i][1], e[i][2], e[i][3]);
        }
    } else {
        // transpose 64k x 64h -> t[h][k], then coalesced 256B-row stores
        __syncthreads();
        #pragma unroll
        for (int i = 0; i < 4; i++)
            #pragma unroll
            for (int j = 0; j < 4; j++)
                sm.t[(hg << 2) + j][(rg << 2) + i] = e[i][j];
        __syncthreads();
        float* dstb = Ek + (size_t)b * HDIM * KLEN + (size_t)hb * KLEN + kc0;
        #pragma unroll
        for (int i = 0; i < 4; i++) {
            int h = sr + 16 * i, k4 = sd << 2;
            float4 o = *(const float4*)(&sm.t[h][k4]);
            *(float4*)(dstb + (size_t)h * KLEN + k4) = o;
        }
    }
}

// ============ Scores + masked softmax ============
// Grid 512 (XCD-swizzled), 512 threads (8 waves). Block = (b, q-pair).
// Thread owns 2 contiguous k. tanh via r = rcp(Eq*Ek + 1): 1 trans + 2 fma
// per element. (Eq0,Eq1,w2) broadcast from LDS as one float4 per h.
__global__ __launch_bounds__(512) void score_kernel(
    const float* __restrict__ Eq, const float* __restrict__ Ek,
    const float* __restrict__ w_v, const int* __restrict__ valid_lens,
    float* __restrict__ p)
{
    __shared__ float4 eqw[HDIM];
    __shared__ float red0[8], red1[8];

    int tid = threadIdx.x, lane = tid & 63, wav = tid >> 6;
    int blk = blockIdx.x;
    int xcd = blk & 7, s = blk >> 3;
    int b = ((s >= 32) ? 8 : 0) + xcd;
    int qp = s & 31;
    int bq0 = b * 64 + qp * 2;
    int vlen = valid_lens[b];

    if (tid < HDIM) {
        float w2 = -2.0f * w_v[tid];
        eqw[tid] = make_float4(Eq[(size_t)bq0 * HDIM + tid],
                               Eq[(size_t)(bq0 + 1) * HDIM + tid], w2, 0.f);
    }
    __syncthreads();

    int k0 = tid << 1;
    float s00 = -1e30f, s01 = -1e30f, s10 = -1e30f, s11 = -1e30f;
    if (k0 < vlen) {
        const float* ekp = Ek + (size_t)b * HDIM * KLEN + k0;
        float a00 = 0.f, a01 = 0.f, a10 = 0.f, a11 = 0.f;
        #pragma unroll 4
        for (int h = 0; h < HDIM; h++) {
            float2 ek = *(const float2*)(ekp + (size_t)h * KLEN);
            float4 e  = eqw[h];
            a00 = fmaf(e.z, __builtin_amdgcn_rcpf(fmaf(e.x, ek.x, 1.f)), a00);
            a01 = fmaf(e.z, __builtin_amdgcn_rcpf(fmaf(e.x, ek.y, 1.f)), a01);
            a10 = fmaf(e.z, __builtin_amdgcn_rcpf(fmaf(e.y, ek.x, 1.f)), a10);
            a11 = fmaf(e.z, __builtin_amdgcn_rcpf(fmaf(e.y, ek.y, 1.f)), a11);
        }
        s00 = a00; s10 = a10;
        if (k0 + 1 < vlen) { s01 = a01; s11 = a11; }
    }

    float m0 = fmaxf(s00, s01), m1 = fmaxf(s10, s11);
    #pragma unroll
    for (int off = 32; off > 0; off >>= 1) {
        m0 = fmaxf(m0, __shfl_xor(m0, off, 64));
        m1 = fmaxf(m1, __shfl_xor(m1, off, 64));
    }
    if (lane == 0) { red0[wav] = m0; red1[wav] = m1; }
    __syncthreads();
    m0 = red0[0]; m1 = red1[0];
    #pragma unroll
    for (int i = 1; i < 8; i++) {
        m0 = fmaxf(m0, red0[i]);
        m1 = fmaxf(m1, red1[i]);
    }

    float e00 = __expf(s00 - m0), e01 = __expf(s01 - m0);   // masked -> exact 0
    float e10 = __expf(s10 - m1), e11 = __expf(s11 - m1);
    float t0 = e00 + e01, t1 = e10 + e11;
    #pragma unroll
    for (int off = 32; off > 0; off >>= 1) {
        t0 += __shfl_xor(t0, off, 64);
        t1 += __shfl_xor(t1, off, 64);
    }
    __syncthreads();
    if (lane == 0) { red0[wav] = t0; red1[wav] = t1; }
    __syncthreads();
    t0 = red0[0]; t1 = red1[0];
    #pragma unroll
    for (int i = 1; i < 8; i++) { t0 += red0[i]; t1 += red1[i]; }
    float inv0 = 1.0f / t0, inv1 = 1.0f / t1;

    float* p0 = p + (size_t)bq0 * KLEN + k0;
    *(float2*)(p0)        = make_float2(e00 * inv0, e01 * inv0);
    *(float2*)(p0 + KLEN) = make_float2(e10 * inv1, e11 * inv1);
}

// ============ attn @ V ============
// v2: wave-exclusive k-slices kill the 4x V L1 redundancy.
// Grid 1024 = (16 b) x (8 qt) x (8 kq), XCD-swizzled, 256 thr (4 waves).
// Wave w owns k in [kbeg+32w, kbeg+32w+32); thread accumulates all 8 q
// for its d-quad (32 fma/k; p broadcast from LDS as 2 aligned b128).
// Cross-wave LDS reduction, wave 0 stores. p==0 beyond vlen -> no masking.
__global__ __launch_bounds__(256) void av_kernel(
    const float* __restrict__ p, const float* __restrict__ values,
    float* __restrict__ part)
{
    __shared__ float pt[128][12];       // [k][q], pad 12 keeps b128 align
    __shared__ float slab[3][8][256];   // cross-wave partials (24 KB)

    int blk = blockIdx.x;
    int xcd = blk & 7, s = blk >> 3;
    int b = ((s >> 6) << 3) | xcd;
    int r = s & 63, qt = r >> 3, kq = r & 7;
    int tid = threadIdx.x, lane = tid & 63, w = tid >> 6;
    int kbeg = kq << 7;
    int bq0 = b * 64 + qt * 8;

    {   // stage p[8q][128k] -> pt[k][q]
        int q = tid >> 5, k4 = (tid & 31) << 2;
        float4 pv = *(const float4*)(p + (size_t)(bq0 + q) * KLEN + kbeg + k4);
        pt[k4 + 0][q] = pv.x;
        pt[k4 + 1][q] = pv.y;
        pt[k4 + 2][q] = pv.z;
        pt[k4 + 3][q] = pv.w;
    }
    __syncthreads();

    const float* vb = values + ((size_t)b * KLEN + kbeg + (w << 5)) * DDIM + (lane << 2);
    float4 acc[8];
    #pragma unroll
    for (int q = 0; q < 8; q++) acc[q] = make_float4(0.f, 0.f, 0.f, 0.f);

    #pragma unroll 4
    for (int k = 0; k < 32; k++) {
        float4 v  = *(const float4*)(vb + (size_t)k * DDIM);
        float4 p0 = *(const float4*)(&pt[(w << 5) + k][0]);
        float4 p1 = *(const float4*)(&pt[(w << 5) + k][4]);
        float pq[8] = {p0.x, p0.y, p0.z, p0.w, p1.x, p1.y, p1.z, p1.w};
        #pragma unroll
        for (int q = 0; q < 8; q++) {
            acc[q].x = fmaf(pq[q], v.x, acc[q].x);
            acc[q].y = fmaf(pq[q], v.y, acc[q].y);
            acc[q].z = fmaf(pq[q], v.z, acc[q].z);
            acc[q].w = fmaf(pq[q], v.w, acc[q].w);
        }
    }

    if (w > 0) {
        #pragma unroll
        for (int q = 0; q < 8; q++)
            *(float4*)(&slab[w - 1][q][lane << 2]) = acc[q];
    }
    __syncthreads();
    if (w == 0) {
        #pragma unroll
        for (int s3 = 0; s3 < 3; s3++)
            #pragma unroll
            for (int q = 0; q < 8; q++) {
                float4 t = *(const float4*)(&slab[s3][q][lane << 2]);
                acc[q].x += t.x; acc[q].y += t.y; acc[q].z += t.z; acc[q].w += t.w;
            }
        float* d0 = part + ((size_t)kq * 1024 + bq0) * DDIM + (lane << 2);
        #pragma unroll
        for (int q = 0; q < 8; q++)
            *(float4*)(d0 + (size_t)q * DDIM) = acc[q];
    }
}

// ============ sum 8 k-partials ============
__global__ __launch_bounds__(256) void combine_kernel(
    const float* __restrict__ part, float* __restrict__ out)
{
    int i = blockIdx.x * 256 + threadIdx.x;        // 65536 float4 slots
    const float4* p4 = (const float4*)part;
    float4 a = p4[i];
    #pragma unroll
    for (int j = 1; j < 8; j++) {
        float4 v = p4[(size_t)j * 65536 + i];
        a.x += v.x; a.y += v.y; a.z += v.z; a.w += v.w;
    }
    ((float4*)out)[i] = a;
}

extern "C" void kernel_launch(void* const* d_in, const int* in_sizes, int n_in,
                              void* d_out, int out_size, void* d_ws, size_t ws_size,
                              hipStream_t stream) {
    const float* queries    = (const float*)d_in[0]; // [16,64,256]
    const float* keys       = (const float*)d_in[1]; // [16,1024,256]
    const float* values     = (const float*)d_in[2]; // [16,1024,256]
    const int*   valid_lens = (const int*)d_in[3];   // [16]
    const float* W_q        = (const float*)d_in[4]; // [256,128]
    const float* W_k        = (const float*)d_in[5]; // [256,128]
    const float* w_v        = (const float*)d_in[6]; // [128]

    float* Eq   = (float*)d_ws;            // 1024*128     = 512 KB
    float* Ek   = Eq + 131072;             // 16*128*1024  = 8 MB
    float* p    = Ek + 2097152;            // 1024*1024    = 4 MB
    float* part = Ek;                      // alias: Ek dead after score; 8 MB exact

    proj_kernel<<<544, 256, 0, stream>>>(queries, keys, W_q, W_k, Eq, Ek);
    score_kernel<<<512, 512, 0, stream>>>(Eq, Ek, w_v, valid_lens, p);
    av_kernel<<<1024, 256, 0, stream>>>(p, values, part);
    combine_kernel<<<256, 256, 0, stream>>>(part, (float*)d_out);
}